// Round 20
// baseline (1318.780 us; speedup 1.0000x reference)
//
#include <hip/hip_runtime.h>
#include <hip/hip_bf16.h>
#include <cstdint>
#include <cstddef>

#define B_ 2
#define S_ 2048
#define E_ 512
#define H_ 8
#define HD_ 64
#define F_ 2048
#define L_ 2
#define V_ 32000
#define MROWS (B_*S_)   // 4096

typedef __attribute__((ext_vector_type(4))) float f32x4;
typedef __attribute__((ext_vector_type(8))) short short8;

__device__ __forceinline__ void splitbf(float f, unsigned short& h, unsigned short& l) {
    __hip_bfloat16 hb = __float2bfloat16(f);
    __hip_bfloat16 lb = __float2bfloat16(f - __bfloat162float(hb));
    h = *(unsigned short*)&hb; l = *(unsigned short*)&lb;
}

// ---------------------------------------------------------------------------
// Scan: per batch, rel_pos (cummax of starts, s=0 forced) and seg_begin.
// ---------------------------------------------------------------------------
__global__ __launch_bounds__(256)
void scan_kernel(const int* __restrict__ tokens, const int* __restrict__ start_id_p,
                 int* __restrict__ rel_pos, int* __restrict__ seg_begin) {
    int b = blockIdx.x;
    int tid = threadIdx.x;
    __shared__ int lsc[256], sbc[256], lsp[256], sbp[256];
    int start_id = *start_id_p;
    const int* tb = tokens + b * S_;
    int base = tid * 8;
    int toks[8];
#pragma unroll
    for (int i = 0; i < 8; i++) toks[i] = tb[base + i];
    int ls = -1, sb = -1;
#pragma unroll
    for (int i = 0; i < 8; i++) {
        int s = base + i;
        bool st0 = (toks[i] == start_id);
        if (st0 || s == 0) ls = s;
        if (st0) sb = s;
    }
    lsc[tid] = ls; sbc[tid] = sb;
    __syncthreads();
    if (tid == 0) {
        int rl = -1, rs = -1;
        for (int t = 0; t < 256; t++) {
            lsp[t] = rl; sbp[t] = rs;
            if (lsc[t] >= 0) rl = lsc[t];
            if (sbc[t] >= 0) rs = sbc[t];
        }
    }
    __syncthreads();
    int cls = lsp[tid], csb = sbp[tid];
#pragma unroll
    for (int i = 0; i < 8; i++) {
        int s = base + i;
        bool st0 = (toks[i] == start_id);
        if (st0 || s == 0) cls = s;
        if (st0) csb = s;
        rel_pos[b * S_ + s]  = s - (cls < 0 ? 0 : cls);
        seg_begin[b * S_ + s] = (csb < 0 ? 0 : csb);
    }
}

// ---------------------------------------------------------------------------
// Embedding: x = we[tok] + pe[rel]; also emit bf16 hi/lo split of x.
// ---------------------------------------------------------------------------
__global__ __launch_bounds__(128)
void embed_kernel(const int* __restrict__ tokens, const int* __restrict__ rel_pos,
                  const float* __restrict__ we, const float* __restrict__ pe,
                  float* __restrict__ x,
                  unsigned short* __restrict__ oh, unsigned short* __restrict__ ol) {
    int row = blockIdx.x;
    int tid = threadIdx.x;
    int tok = tokens[row];
    int rp  = rel_pos[row];
    float4 av = ((const float4*)(we + (size_t)tok * E_))[tid];
    float4 pv = ((const float4*)(pe + (size_t)rp  * E_))[tid];
    float4 r;
    r.x = av.x + pv.x; r.y = av.y + pv.y; r.z = av.z + pv.z; r.w = av.w + pv.w;
    ((float4*)(x + (size_t)row * E_))[tid] = r;
    ushort4 hv, lv;
    splitbf(r.x, hv.x, lv.x); splitbf(r.y, hv.y, lv.y);
    splitbf(r.z, hv.z, lv.z); splitbf(r.w, hv.w, lv.w);
    size_t o = (size_t)row * E_ + tid * 4;
    *(ushort4*)(oh + o) = hv;
    *(ushort4*)(ol + o) = lv;
}

// ---------------------------------------------------------------------------
// fp32 GEMM: no-workspace fallback for the unembed. BT=true: C = A * B^T.
// ---------------------------------------------------------------------------
template<bool BT, bool RELU>
__global__ __launch_bounds__(256)
void gemm_kernel(const float* __restrict__ A, const float* __restrict__ Bm,
                 const float* __restrict__ bias, float* __restrict__ C,
                 int M, int N, int K) {
    __shared__ float As[16][64];
    __shared__ float Bs[16][64];
    int tid = threadIdx.x;
    int tx = tid & 15, ty = tid >> 4;
    int m0 = blockIdx.y * 64, n0 = blockIdx.x * 64;
    float acc[4][4] = {};
    int ar  = tid >> 2;
    int ak4 = (tid & 3) << 2;
    for (int k0 = 0; k0 < K; k0 += 16) {
        float4 av = *(const float4*)(A + (size_t)(m0 + ar) * K + k0 + ak4);
        As[ak4 + 0][ar] = av.x; As[ak4 + 1][ar] = av.y;
        As[ak4 + 2][ar] = av.z; As[ak4 + 3][ar] = av.w;
        if (BT) {
            int c = tid >> 2, kk4 = (tid & 3) << 2;
            float4 bv = *(const float4*)(Bm + (size_t)(n0 + c) * K + k0 + kk4);
            Bs[kk4 + 0][c] = bv.x; Bs[kk4 + 1][c] = bv.y;
            Bs[kk4 + 2][c] = bv.z; Bs[kk4 + 3][c] = bv.w;
        } else {
            int kk = tid >> 4, c4 = (tid & 15) << 2;
            float4 bv = *(const float4*)(Bm + (size_t)(k0 + kk) * N + n0 + c4);
            *(float4*)&Bs[kk][c4] = bv;
        }
        __syncthreads();
#pragma unroll
        for (int kk = 0; kk < 16; kk++) {
            float a4[4], b4[4];
            *(float4*)a4 = *(const float4*)&As[kk][ty << 2];
            *(float4*)b4 = *(const float4*)&Bs[kk][tx << 2];
#pragma unroll
            for (int i = 0; i < 4; i++)
#pragma unroll
                for (int j = 0; j < 4; j++)
                    acc[i][j] = fmaf(a4[i], b4[j], acc[i][j]);
        }
        __syncthreads();
    }
    float bvv[4] = {0.f, 0.f, 0.f, 0.f};
    if (bias) {
#pragma unroll
        for (int j = 0; j < 4; j++) bvv[j] = bias[n0 + (tx << 2) + j];
    }
#pragma unroll
    for (int i = 0; i < 4; i++) {
        float o[4];
#pragma unroll
        for (int j = 0; j < 4; j++) {
            float v = acc[i][j] + bvv[j];
            if (RELU) v = fmaxf(v, 0.0f);
            o[j] = v;
        }
        *(float4*)(C + (size_t)(m0 + (ty << 2) + i) * N + n0 + (tx << 2)) = *(float4*)o;
    }
}

// ---------------------------------------------------------------------------
// Flash-style tiled attention. One block = 32 queries x (h, b); 256 threads.
// Thread = (qi = t>>3, sub = t&7) owns query q0+qi, dims d = sub*8..+7.
// K/V staged in LDS in 64-key tiles; online softmax (m, l, acc[8]).
// Valid keys for q: [seg_begin(q), q]; seg_begin monotone => block tile range
// starts at seg_begin(q0) & ~63. Masked scores = -3e38 -> expf underflows to 0.
// Barriers all non-divergent. kqv: [B,S,1536], col = h*192 + {K:0,Q:64,V:128}+d.
// Output: bf16 hi/lo split (feeds WO MFMA GEMM).
// ---------------------------------------------------------------------------
__global__ __launch_bounds__(256)
void attn_kernel(const float* __restrict__ kqv, const int* __restrict__ seg_begin,
                 unsigned short* __restrict__ oh, unsigned short* __restrict__ ol) {
    __shared__ float Qs[32][68];
    __shared__ float Ks[64][68];
    __shared__ float Vs[64][68];
    __shared__ float sc[32][66];
    int t = threadIdx.x;
    int h = blockIdx.y, b = blockIdx.z;
    int q0 = blockIdx.x * 32;
    int qi = t >> 3, sub = t & 7;
    int q  = q0 + qi;
    int d0 = sub * 8;
    const size_t rs = 1536;
    const float* base = kqv + (size_t)b * S_ * rs + h * 192;

    {   // stage Q
        const float* qp = base + (size_t)q * rs + 64 + d0;
        *(float4*)&Qs[qi][d0]     = *(const float4*)(qp);
        *(float4*)&Qs[qi][d0 + 4] = *(const float4*)(qp + 4);
    }
    int my_sb = seg_begin[b * S_ + q];
    int sb0   = seg_begin[b * S_ + q0];
    int qhi   = q0 + 31;

    float m = -3.0e38f, l = 0.f;
    float acc[8] = {};

    for (int kt = sb0 & ~63; kt <= qhi; kt += 64) {
        {   // stage K,V
            int r = t >> 2, cs = (t & 3) << 4;
            const float* kp = base + (size_t)(kt + r) * rs + cs;   // K
            const float* vp = kp + 128;                            // V
            *(float4*)&Ks[r][cs]      = *(const float4*)(kp);
            *(float4*)&Ks[r][cs + 4]  = *(const float4*)(kp + 4);
            *(float4*)&Ks[r][cs + 8]  = *(const float4*)(kp + 8);
            *(float4*)&Ks[r][cs + 12] = *(const float4*)(kp + 12);
            *(float4*)&Vs[r][cs]      = *(const float4*)(vp);
            *(float4*)&Vs[r][cs + 4]  = *(const float4*)(vp + 4);
            *(float4*)&Vs[r][cs + 8]  = *(const float4*)(vp + 8);
            *(float4*)&Vs[r][cs + 12] = *(const float4*)(vp + 12);
        }
        __syncthreads();
#pragma unroll
        for (int j = 0; j < 8; j++) {
            int kk = sub + j * 8;
            int kg = kt + kk;
            float s = -3.0e38f;
            if (kg >= my_sb && kg <= q) {
                float d = 0.f;
#pragma unroll
                for (int e = 0; e < 64; e += 4) {
                    float4 q4 = *(const float4*)&Qs[qi][e];
                    float4 k4 = *(const float4*)&Ks[kk][e];
                    d += q4.x * k4.x + q4.y * k4.y + q4.z * k4.z + q4.w * k4.w;
                }
                s = d * 0.125f;
            }
            sc[qi][kk] = s;
        }
        __syncthreads();
        float tmax = -3.0e38f;
#pragma unroll
        for (int kk = 0; kk < 64; kk++) tmax = fmaxf(tmax, sc[qi][kk]);
        if (tmax > -1.0e30f) {
            float nm = fmaxf(m, tmax);
            float corr = expf(m - nm);
            l *= corr;
#pragma unroll
            for (int j = 0; j < 8; j++) acc[j] *= corr;
            float lsum = 0.f;
            for (int kk = 0; kk < 64; kk++) {
                float p = expf(sc[qi][kk] - nm);
                lsum += p;
                float4 va = *(const float4*)&Vs[kk][d0];
                float4 vb = *(const float4*)&Vs[kk][d0 + 4];
                acc[0] += p * va.x; acc[1] += p * va.y;
                acc[2] += p * va.z; acc[3] += p * va.w;
                acc[4] += p * vb.x; acc[5] += p * vb.y;
                acc[6] += p * vb.z; acc[7] += p * vb.w;
            }
            l += lsum;
            m = nm;
        }
        __syncthreads();
    }
    float inv = 1.0f / l;
    size_t o = ((size_t)b * S_ + q) * E_ + h * HD_ + d0;
#pragma unroll
    for (int j = 0; j < 8; j++) splitbf(acc[j] * inv, oh[o + j], ol[o + j]);
}

// ---------------------------------------------------------------------------
// LayerNorm + residual: x += LN(y)*g + b; also emit bf16 hi/lo split of x.
// ---------------------------------------------------------------------------
__global__ __launch_bounds__(256)
void ln_res_kernel(const float* __restrict__ y, const float* __restrict__ g,
                   const float* __restrict__ bb, float* __restrict__ x,
                   unsigned short* __restrict__ oh, unsigned short* __restrict__ ol) {
    int row = blockIdx.x, tid = threadIdx.x;
    __shared__ float red[256];
    const float* yr = y + (size_t)row * E_;
    float v0 = yr[tid], v1 = yr[tid + 256];
    red[tid] = v0 + v1; __syncthreads();
    for (int st = 128; st > 0; st >>= 1) {
        if (tid < st) red[tid] += red[tid + st];
        __syncthreads();
    }
    float mean = red[0] * (1.0f / E_); __syncthreads();
    float d0 = v0 - mean, d1 = v1 - mean;
    red[tid] = d0 * d0 + d1 * d1; __syncthreads();
    for (int st = 128; st > 0; st >>= 1) {
        if (tid < st) red[tid] += red[tid + st];
        __syncthreads();
    }
    float var = red[0] * (1.0f / E_);
    float rstd = rsqrtf(var + 1e-6f);
    float* xr = x + (size_t)row * E_;
    float n0 = xr[tid]       + d0 * rstd * g[tid]       + bb[tid];
    float n1 = xr[tid + 256] + d1 * rstd * g[tid + 256] + bb[tid + 256];
    xr[tid] = n0; xr[tid + 256] = n1;
    size_t o = (size_t)row * E_;
    splitbf(n0, oh[o + tid],       ol[o + tid]);
    splitbf(n1, oh[o + tid + 256], ol[o + tid + 256]);
}

// ---------------------------------------------------------------------------
// Split fp32 -> bf16 hi/lo (word_embed only). 4 elems/thread.
// ---------------------------------------------------------------------------
__global__ __launch_bounds__(256)
void split_bf16_kernel(const float* __restrict__ src,
                       unsigned short* __restrict__ hi,
                       unsigned short* __restrict__ lo, int n4) {
    int i = blockIdx.x * 256 + threadIdx.x;
    if (i >= n4) return;
    float4 v = ((const float4*)src)[i];
    ushort4 hv, lv;
    splitbf(v.x, hv.x, lv.x); splitbf(v.y, hv.y, lv.y);
    splitbf(v.z, hv.z, lv.z); splitbf(v.w, hv.w, lv.w);
    ((ushort4*)hi)[i] = hv;
    ((ushort4*)lo)[i] = lv;
}

// ---------------------------------------------------------------------------
// Split + transpose: W [K,N] fp32 -> Wh,Wl [N,K] bf16. 32x32 LDS tiles.
// ---------------------------------------------------------------------------
__global__ __launch_bounds__(256)
void split_tr_kernel(const float* __restrict__ W, unsigned short* __restrict__ oh,
                     unsigned short* __restrict__ ol, int K, int N) {
    __shared__ float t[32][33];
    int n0 = blockIdx.x * 32, k0 = blockIdx.y * 32;
    int c = threadIdx.x & 31, r = threadIdx.x >> 5;
#pragma unroll
    for (int i = 0; i < 4; i++) {
        int kk = r + i * 8;
        t[kk][c] = W[(size_t)(k0 + kk) * N + n0 + c];
    }
    __syncthreads();
#pragma unroll
    for (int i = 0; i < 4; i++) {
        int nn = r + i * 8;
        float f = t[c][nn];
        size_t o = (size_t)(n0 + nn) * K + k0 + c;
        splitbf(f, oh[o], ol[o]);
    }
}

// ---------------------------------------------------------------------------
// Split-bf16 MFMA GEMM: C[M,N] = A[M,K] @ B[N,K]^T (+bias, opt relu)
// 3-term split product. 128x128 tile, BK=32, 4 waves (2x2), 64x64 out/wave.
// Layouts (m89-verified). LDS rows padded to 40 bf16 (2 lanes/bank, free).
// WF32: write fp32 C.  WSPLIT: write bf16 hi/lo split (post-relu/bias).
// XCD-aware bijective block swizzle (T1): when nwg%8==0, hardware blocks on
// one XCD get a contiguous chunk of logical tiles -> A-panel L2 locality.
// ---------------------------------------------------------------------------
template<bool RELU, bool WF32, bool WSPLIT>
__global__ __launch_bounds__(256)
void gemm_mfma_kernel(const unsigned short* __restrict__ ah_g,
                      const unsigned short* __restrict__ al_g,
                      const unsigned short* __restrict__ bh_g,
                      const unsigned short* __restrict__ bl_g,
                      const float* __restrict__ bias,
                      float* __restrict__ C,
                      unsigned short* __restrict__ oh,
                      unsigned short* __restrict__ ol,
                      int M, int N, int K) {
    __shared__ short Ash[128][40], Asl[128][40];
    __shared__ short Bsh[128][40], Bsl[128][40];
    int tid  = threadIdx.x;
    int lane = tid & 63, wid = tid >> 6;
    int wr = wid >> 1, wc = wid & 1;
    int fr = lane & 15, fq = lane >> 4;

    // XCD swizzle (bijective since all our grids have nwg % 8 == 0)
    int gx = gridDim.x, nwg = gx * gridDim.y;
    int bid = blockIdx.y * gx + blockIdx.x;
    if ((nwg & 7) == 0) {
        int cpx = nwg >> 3;
        bid = (bid & 7) * cpx + (bid >> 3);
    }
    int bx = bid % gx, by = bid / gx;
    int m0 = by * 128, n0 = bx * 128;

    f32x4 acc[4][4] = {};

    int srow = tid >> 1;
    int scg0 = (tid & 1) << 1;
    const size_t arow = (size_t)(m0 + srow) * K;
    const size_t brow = (size_t)(n0 + srow) * K;

    for (int k0 = 0; k0 < K; k0 += 32) {
#pragma unroll
        for (int g = 0; g < 2; g++) {
            int c8 = (scg0 + g) * 8;
            *(short8*)&Ash[srow][c8] = *(const short8*)(ah_g + arow + k0 + c8);
            *(short8*)&Asl[srow][c8] = *(const short8*)(al_g + arow + k0 + c8);
            *(short8*)&Bsh[srow][c8] = *(const short8*)(bh_g + brow + k0 + c8);
            *(short8*)&Bsl[srow][c8] = *(const short8*)(bl_g + brow + k0 + c8);
        }
        __syncthreads();

        short8 ah[4], al[4], bh[4], bl[4];
#pragma unroll
        for (int m = 0; m < 4; m++) {
            ah[m] = *(const short8*)&Ash[wr * 64 + m * 16 + fr][fq * 8];
            al[m] = *(const short8*)&Asl[wr * 64 + m * 16 + fr][fq * 8];
        }
#pragma unroll
        for (int n = 0; n < 4; n++) {
            bh[n] = *(const short8*)&Bsh[wc * 64 + n * 16 + fr][fq * 8];
            bl[n] = *(const short8*)&Bsl[wc * 64 + n * 16 + fr][fq * 8];
        }
#pragma unroll
        for (int m = 0; m < 4; m++)
#pragma unroll
            for (int n = 0; n < 4; n++) {
                acc[m][n] = __builtin_amdgcn_mfma_f32_16x16x32_bf16(ah[m], bh[n], acc[m][n], 0, 0, 0);
                acc[m][n] = __builtin_amdgcn_mfma_f32_16x16x32_bf16(ah[m], bl[n], acc[m][n], 0, 0, 0);
                acc[m][n] = __builtin_amdgcn_mfma_f32_16x16x32_bf16(al[m], bh[n], acc[m][n], 0, 0, 0);
            }
        __syncthreads();
    }

#pragma unroll
    for (int m = 0; m < 4; m++) {
        int rbase = m0 + wr * 64 + m * 16 + fq * 4;
#pragma unroll
        for (int n = 0; n < 4; n++) {
            int col = n0 + wc * 64 + n * 16 + fr;
            float bv = bias ? bias[col] : 0.f;
#pragma unroll
            for (int j = 0; j < 4; j++) {
                float v = acc[m][n][j] + bv;
                if (RELU) v = fmaxf(v, 0.0f);
                size_t o = (size_t)(rbase + j) * N + col;
                if (WF32)   C[o] = v;
                if (WSPLIT) splitbf(v, oh[o], ol[o]);
            }
        }
    }
}

// ---------------------------------------------------------------------------
// Memory plan (decided from REAL ws_size; deterministic):
//   d_ws (>= 8.5 MB): x + scan.  (>= 82.3 MB): + we/x splits for the unembed
//     (must be live while the final GEMM overwrites all of d_out).
//   d_out scratch (all dead before the final GEMM): kqv 25.2M | tmp 8.4M |
//     act split 2x4.2M | hact split 2x16.8M | weight splits 25.2M  (~100 MB).
// ---------------------------------------------------------------------------
extern "C" void kernel_launch(void* const* d_in, const int* in_sizes, int n_in,
                              void* d_out, int out_size, void* d_ws, size_t ws_size,
                              hipStream_t stream) {
    const int*   tokens = (const int*)  d_in[0];
    const float* we     = (const float*)d_in[1];
    const float* pe     = (const float*)d_in[2];
    const float* KQV    = (const float*)d_in[3];
    const float* WO     = (const float*)d_in[4];
    const float* Wup    = (const float*)d_in[5];
    const float* bup    = (const float*)d_in[6];
    const float* Wdn    = (const float*)d_in[7];
    const float* bdn    = (const float*)d_in[8];
    const float* g1     = (const float*)d_in[9];
    const float* be1    = (const float*)d_in[10];
    const float* g2     = (const float*)d_in[11];
    const float* be2    = (const float*)d_in[12];
    const float* ub     = (const float*)d_in[13];
    const int*   sid    = (const int*)  d_in[14];
    float* out = (float*)d_out;

    char* ws = (char*)d_ws;
    char* ob = (char*)d_out;

    const size_t SZ_X    = (size_t)MROWS * E_ * 4;       //  8,388,608
    const size_t SZ_SCAN = 2 * (size_t)B_ * S_ * 4;      //     32,768
    const size_t SZ_WEH  = (size_t)V_ * E_ * 2;          // 32,768,000
    const size_t SZ_XH   = (size_t)MROWS * E_ * 2;       //  4,194,304

    // d_ws: x + scan (+ unembed splits when they fit)
    float* x   = (float*)(ws);
    int*  rel  = (int*)  (ws + SZ_X);
    int*  segb = rel + B_ * S_;
    const size_t need_mfma_unembed = SZ_X + SZ_SCAN + 2 * SZ_WEH + 2 * SZ_XH;
    bool unembed_mfma = (ws_size >= need_mfma_unembed);
    unsigned short* weh = (unsigned short*)(ws + SZ_X + SZ_SCAN);
    unsigned short* wel = (unsigned short*)(ws + SZ_X + SZ_SCAN + SZ_WEH);
    unsigned short* xh  = (unsigned short*)(ws + SZ_X + SZ_SCAN + 2 * SZ_WEH);
    unsigned short* xl  = (unsigned short*)(ws + SZ_X + SZ_SCAN + 2 * SZ_WEH + SZ_XH);

    // d_out scratch (all dead before the final unembed GEMM)
    float* kqv  = (float*)(ob);                            // 25,165,824
    float* tmp  = (float*)(ob + 25165824);                 //  8,388,608
    unsigned short* act_h  = (unsigned short*)(ob + 33554432);  // 4,194,304
    unsigned short* act_l  = (unsigned short*)(ob + 37748736);  // 4,194,304
    unsigned short* hact_h = (unsigned short*)(ob + 41943040);  // 16,777,216
    unsigned short* hact_l = (unsigned short*)(ob + 58720256);  // 16,777,216
    unsigned short* wsp    = (unsigned short*)(ob + 75497472);  // 25,165,824
    const size_t LW = 3145728;  // split elems per layer (one of hi/lo)

    scan_kernel<<<dim3(B_), dim3(256), 0, stream>>>(tokens, sid, rel, segb);
    embed_kernel<<<dim3(MROWS), dim3(128), 0, stream>>>(tokens, rel, we, pe, x, act_h, act_l);

    // weight split+transpose
    for (int l = 0; l < L_; l++) {
        unsigned short* lb = wsp + (size_t)l * 2 * LW;
        unsigned short* kqv_h = lb;             unsigned short* kqv_l = lb + 786432;
        unsigned short* wo_h  = lb + 1572864;   unsigned short* wo_l  = lb + 1835008;
        unsigned short* up_h  = lb + 2097152;   unsigned short* up_l  = lb + 3145728;
        unsigned short* dn_h  = lb + 4194304;   unsigned short* dn_l  = lb + 5242880;
        split_tr_kernel<<<dim3(1536 / 32, 512 / 32), 256, 0, stream>>>(
            KQV + (size_t)l * E_ * 3 * E_, kqv_h, kqv_l, 512, 1536);
        split_tr_kernel<<<dim3(512 / 32, 512 / 32), 256, 0, stream>>>(
            WO + (size_t)l * E_ * E_, wo_h, wo_l, 512, 512);
        split_tr_kernel<<<dim3(2048 / 32, 512 / 32), 256, 0, stream>>>(
            Wup + (size_t)l * E_ * F_, up_h, up_l, 512, 2048);
        split_tr_kernel<<<dim3(512 / 32, 2048 / 32), 256, 0, stream>>>(
            Wdn + (size_t)l * F_ * E_, dn_h, dn_l, 2048, 512);
    }

    for (int l = 0; l < L_; l++) {
        unsigned short* lb = wsp + (size_t)l * 2 * LW;
        unsigned short* kqv_h = lb;             unsigned short* kqv_l = lb + 786432;
        unsigned short* wo_h  = lb + 1572864;   unsigned short* wo_l  = lb + 1835008;
        unsigned short* up_h  = lb + 2097152;   unsigned short* up_l  = lb + 3145728;
        unsigned short* dn_h  = lb + 4194304;   unsigned short* dn_l  = lb + 5242880;

        gemm_mfma_kernel<false, true, false><<<dim3(1536 / 128, MROWS / 128), 256, 0, stream>>>(
            act_h, act_l, kqv_h, kqv_l, nullptr, kqv, nullptr, nullptr, MROWS, 1536, 512);

        attn_kernel<<<dim3(S_ / 32, H_, B_), 256, 0, stream>>>(kqv, segb, act_h, act_l);

        gemm_mfma_kernel<false, true, false><<<dim3(512 / 128, MROWS / 128), 256, 0, stream>>>(
            act_h, act_l, wo_h, wo_l, nullptr, tmp, nullptr, nullptr, MROWS, 512, 512);

        ln_res_kernel<<<dim3(MROWS), 256, 0, stream>>>(tmp, g1 + l * E_, be1 + l * E_, x, act_h, act_l);

        gemm_mfma_kernel<true, false, true><<<dim3(2048 / 128, MROWS / 128), 256, 0, stream>>>(
            act_h, act_l, up_h, up_l, bup + (size_t)l * F_, nullptr, hact_h, hact_l, MROWS, 2048, 512);

        gemm_mfma_kernel<false, true, false><<<dim3(512 / 128, MROWS / 128), 256, 0, stream>>>(
            hact_h, hact_l, dn_h, dn_l, bdn + (size_t)l * E_, tmp, nullptr, nullptr, MROWS, 512, 2048);

        bool last = (l == L_ - 1);
        unsigned short* so_h = (last && unembed_mfma) ? xh : act_h;
        unsigned short* so_l = (last && unembed_mfma) ? xl : act_l;
        ln_res_kernel<<<dim3(MROWS), 256, 0, stream>>>(tmp, g2 + l * E_, be2 + l * E_, x, so_h, so_l);
    }

    if (unembed_mfma) {
        split_bf16_kernel<<<dim3(V_ * E_ / 4 / 256), 256, 0, stream>>>(
            we, weh, wel, V_ * E_ / 4);
        gemm_mfma_kernel<false, true, false><<<dim3(V_ / 128, MROWS / 128), 256, 0, stream>>>(
            xh, xl, weh, wel, ub, out, nullptr, nullptr, MROWS, V_, 512);
    } else {
        gemm_kernel<true, false><<<dim3(V_ / 64, MROWS / 64), 256, 0, stream>>>(
            x, we, ub, out, MROWS, V_, E_);
    }
}